// Round 3
// baseline (431.271 us; speedup 1.0000x reference)
//
#include <hip/hip_runtime.h>

typedef unsigned short u16;
typedef __attribute__((ext_vector_type(8))) short bf16x8;   // 8 bf16 = 4 VGPRs
typedef __attribute__((ext_vector_type(4))) float f32x4;

#define MFMA16(A, B, C) __builtin_amdgcn_mfma_f32_16x16x32_bf16(A, B, C, 0, 0, 0)

__device__ __forceinline__ u16 f2bf(float f) {
  union { float f; unsigned u; } x; x.f = f;
  unsigned r = x.u + 0x7fffu + ((x.u >> 16) & 1u);   // RNE
  return (u16)(r >> 16);
}

// ---------------------------------------------------------------------------
// fp32 -> bf16 elementwise (inputs arrive as float32 per the reference).
// n must be a multiple of 2048 (grid covers n/8 threads, 8 elems/thread).
// ---------------------------------------------------------------------------
__global__ __launch_bounds__(256) void cvt_bf16(const float* __restrict__ s,
                                                u16* __restrict__ d, int n) {
  const int i = (blockIdx.x * 256 + threadIdx.x) * 8;
  if (i >= n) return;
  const float4 a = *(const float4*)(s + i);
  const float4 b = *(const float4*)(s + i + 4);
  bf16x8 o;
  o[0] = (short)f2bf(a.x); o[1] = (short)f2bf(a.y);
  o[2] = (short)f2bf(a.z); o[3] = (short)f2bf(a.w);
  o[4] = (short)f2bf(b.x); o[5] = (short)f2bf(b.y);
  o[6] = (short)f2bf(b.z); o[7] = (short)f2bf(b.w);
  *(bf16x8*)(d + i) = o;
}

// ---------------------------------------------------------------------------
// NT GEMM: C[M,N] = A[M,K] @ B[N,K]^T, bf16 in, fp32 accum.
// 128x128 block tile, BK=32, 256 threads (4 waves, each 64x64).
// MODE 0: bf16 out, row-major.
// MODE 1: bf16 out, scattered per-head-transposed: Vt[(b*1024+n)*2048 + s]
// MODE 2: fp32 out, row-major (final output).
// ---------------------------------------------------------------------------
template <int MODE>
__global__ __launch_bounds__(256) void gemm_nt(const u16* __restrict__ A,
                                               const u16* __restrict__ B,
                                               void* __restrict__ Cv,
                                               int M, int N, int K) {
  __shared__ alignas(16) u16 As[128 * 40];   // stride 40 keeps rows 16B-aligned
  __shared__ alignas(16) u16 Bs[128 * 40];
  const int t = threadIdx.x;
  const int lane = t & 63, wave = t >> 6;
  const int quad = lane >> 4, l16 = lane & 15;
  const int m0 = blockIdx.y * 128, n0 = blockIdx.x * 128;
  const int wm = (wave >> 1) * 64, wn = (wave & 1) * 64;

  f32x4 acc[4][4] = {};

  for (int kk = 0; kk < K; kk += 32) {
#pragma unroll
    for (int i = 0; i < 2; i++) {
      int l = t + i * 256;
      int row = l >> 2;
      int c8 = (l & 3) * 8;
      *(bf16x8*)(As + row * 40 + c8) =
          *(const bf16x8*)(A + (size_t)(m0 + row) * K + kk + c8);
      *(bf16x8*)(Bs + row * 40 + c8) =
          *(const bf16x8*)(B + (size_t)(n0 + row) * K + kk + c8);
    }
    __syncthreads();

    bf16x8 af[4], bfr[4];
#pragma unroll
    for (int i = 0; i < 4; i++)
      af[i] = *(const bf16x8*)(As + (wm + i * 16 + l16) * 40 + quad * 8);
#pragma unroll
    for (int j = 0; j < 4; j++)
      bfr[j] = *(const bf16x8*)(Bs + (wn + j * 16 + l16) * 40 + quad * 8);
#pragma unroll
    for (int i = 0; i < 4; i++)
#pragma unroll
      for (int j = 0; j < 4; j++)
        acc[i][j] = MFMA16(af[i], bfr[j], acc[i][j]);
    __syncthreads();
  }

  // C/D layout: col = lane&15, row = quad*4 + r  [m89/m91 verified]
#pragma unroll
  for (int i = 0; i < 4; i++)
#pragma unroll
    for (int j = 0; j < 4; j++)
#pragma unroll
      for (int r = 0; r < 4; r++) {
        int row = m0 + wm + i * 16 + quad * 4 + r;
        int col = n0 + wn + j * 16 + l16;
        float v = acc[i][j][r];
        if (MODE == 2) {
          ((float*)Cv)[(size_t)row * N + col] = v;
        } else if (MODE == 1) {
          ((u16*)Cv)[((size_t)(row >> 11) * 1024 + col) * 2048 + (row & 2047)] =
              f2bf(v);
        } else {
          ((u16*)Cv)[(size_t)row * N + col] = f2bf(v);
        }
      }
}

// ---------------------------------------------------------------------------
// Flash attention, bf16 MFMA. One block = (q-tile of 64) x (b,h).
// 4 waves/block, each wave owns 16 q rows. Chunks of 32 keys:
//   scores (2 key-tiles x 2 k-steps), bias+mask, online softmax,
//   P C-layout -> A-layout via per-wave LDS, P@V against transposed Vt.
// ---------------------------------------------------------------------------
__global__ __launch_bounds__(256) void attn_fwd(const u16* __restrict__ Q,
                                                const u16* __restrict__ Kb_,
                                                const u16* __restrict__ Vt,
                                                const int* __restrict__ mask,
                                                u16* __restrict__ O) {
  constexpr int S = 2048, E = 1024, D = 64;
  __shared__ alignas(16) u16 Pl[4][16 * 40];   // per-wave P tile, stride 40
  const int t = threadIdx.x;
  const int lane = t & 63, wave = t >> 6;
  const int quad = lane >> 4, l16 = lane & 15;
  const int bh = blockIdx.y, b = bh >> 4, h = bh & 15;
  const int q0 = blockIdx.x * 64 + wave * 16;

  const u16* qp = Q + ((size_t)(b * S) + q0 + l16) * E + h * D;
  const bf16x8 aq0 = *(const bf16x8*)(qp + quad * 8);
  const bf16x8 aq1 = *(const bf16x8*)(qp + 32 + quad * 8);

  const u16* kbase = Kb_ + (size_t)(b * S) * E + h * D;
  const u16* vbase = Vt + (size_t)(b * 16 + h) * D * S;
  const int* mrow = mask + b * S;

  float mr[4], lr[4];
  f32x4 accO[4] = {};
#pragma unroll
  for (int r = 0; r < 4; r++) { mr[r] = -1e30f; lr[r] = 0.0f; }

  u16* pl = Pl[wave];
  const float LOG2E = 1.44269504f;

  for (int kc = 0; kc < S; kc += 32) {
    const u16* kp0 = kbase + (size_t)(kc + l16) * E;
    const u16* kp1 = kp0 + 16 * E;
    bf16x8 bk00 = *(const bf16x8*)(kp0 + quad * 8);
    bf16x8 bk01 = *(const bf16x8*)(kp0 + 32 + quad * 8);
    bf16x8 bk10 = *(const bf16x8*)(kp1 + quad * 8);
    bf16x8 bk11 = *(const bf16x8*)(kp1 + 32 + quad * 8);
    f32x4 s0 = {}, s1 = {};
    s0 = MFMA16(aq0, bk00, s0);
    s0 = MFMA16(aq1, bk01, s0);
    s1 = MFMA16(aq0, bk10, s1);
    s1 = MFMA16(aq1, bk11, s1);

    const int mk0 = mrow[kc + l16];
    const int mk1 = mrow[kc + 16 + l16];
    const int k0 = kc + l16, k1 = k0 + 16;

#pragma unroll
    for (int r = 0; r < 4; r++) {
      const int qg = q0 + quad * 4 + r;
      // scale 1/sqrt(64) + mirror bias -0.5*|j-(S-1-i)|/S
      float v0 = s0[r] * 0.125f - 2.44140625e-4f * fabsf((float)(k0 + qg - 2047));
      float v1 = s1[r] * 0.125f - 2.44140625e-4f * fabsf((float)(k1 + qg - 2047));
      if (mk0) v0 = -1e30f;
      if (mk1) v1 = -1e30f;
      float mx = fmaxf(v0, v1);
      mx = fmaxf(mx, __shfl_xor(mx, 1));
      mx = fmaxf(mx, __shfl_xor(mx, 2));
      mx = fmaxf(mx, __shfl_xor(mx, 4));
      mx = fmaxf(mx, __shfl_xor(mx, 8));
      const float mnew = fmaxf(mr[r], mx);
      const float alpha = __builtin_exp2f((mr[r] - mnew) * LOG2E);
      mr[r] = mnew;
      const float p0 = __builtin_exp2f((v0 - mnew) * LOG2E);
      const float p1 = __builtin_exp2f((v1 - mnew) * LOG2E);
      float rs = p0 + p1;
      rs += __shfl_xor(rs, 1);
      rs += __shfl_xor(rs, 2);
      rs += __shfl_xor(rs, 4);
      rs += __shfl_xor(rs, 8);
      lr[r] = lr[r] * alpha + rs;
#pragma unroll
      for (int tt = 0; tt < 4; tt++) accO[tt][r] *= alpha;
      pl[(quad * 4 + r) * 40 + l16] = f2bf(p0);
      pl[(quad * 4 + r) * 40 + l16 + 16] = f2bf(p1);
    }
    // make cross-lane P writes visible before the A-frag reload
    __syncthreads();
    const bf16x8 ap = *(const bf16x8*)(pl + l16 * 40 + quad * 8);
#pragma unroll
    for (int tt = 0; tt < 4; tt++) {
      bf16x8 bv = *(const bf16x8*)(vbase + (size_t)(tt * 16 + l16) * S + kc + quad * 8);
      accO[tt] = MFMA16(ap, bv, accO[tt]);
    }
    __syncthreads();   // protect Pl against next iteration's writes
  }

#pragma unroll
  for (int r = 0; r < 4; r++) {
    const float inv = 1.0f / lr[r];
    const int qg = q0 + quad * 4 + r;
#pragma unroll
    for (int tt = 0; tt < 4; tt++)
      O[((size_t)(b * S) + qg) * E + h * D + tt * 16 + l16] =
          f2bf(accO[tt][r] * inv);
  }
}

// ---------------------------------------------------------------------------
extern "C" void kernel_launch(void* const* d_in, const int* in_sizes, int n_in,
                              void* d_out, int out_size, void* d_ws, size_t ws_size,
                              hipStream_t stream) {
  const float* x  = (const float*)d_in[0];   // fp32 per the reference
  const float* Wq = (const float*)d_in[1];
  const float* Wk = (const float*)d_in[2];
  const float* Wv = (const float*)d_in[3];
  const float* Wo = (const float*)d_in[4];
  const int* mask = (const int*)d_in[5];     // bool -> int32

  const int M = 4096, N = 1024, K = 1024;    // M = B*S
  const int NE = M * N;                      // 4,194,304
  const int NW = N * K;                      // 1,048,576

  u16* xb  = (u16*)d_ws;                     // bf16 copies of inputs
  u16* Wqb = xb + NE;
  u16* Wkb = Wqb + NW;
  u16* Wvb = Wkb + NW;
  u16* Wob = Wvb + NW;
  u16* Qb  = Wob + NW;                       // [4096,1024] bf16
  u16* Kb  = Qb + NE;
  u16* Vt  = Kb + NE;                        // [B*H, 64, 2048] transposed
  u16* Ao  = Vt + NE;                        // attention out [4096,1024]

  dim3 blk(256);
  cvt_bf16<<<NE / 2048, blk, 0, stream>>>(x, xb, NE);
  cvt_bf16<<<NW / 2048, blk, 0, stream>>>(Wq, Wqb, NW);
  cvt_bf16<<<NW / 2048, blk, 0, stream>>>(Wk, Wkb, NW);
  cvt_bf16<<<NW / 2048, blk, 0, stream>>>(Wv, Wvb, NW);
  cvt_bf16<<<NW / 2048, blk, 0, stream>>>(Wo, Wob, NW);

  dim3 gg(N / 128, M / 128);
  gemm_nt<0><<<gg, blk, 0, stream>>>(xb, Wqb, Qb, M, N, K);
  gemm_nt<0><<<gg, blk, 0, stream>>>(xb, Wkb, Kb, M, N, K);
  gemm_nt<1><<<gg, blk, 0, stream>>>(xb, Wvb, Vt, M, N, K);
  attn_fwd<<<dim3(32, 32), blk, 0, stream>>>(Qb, Kb, Vt, mask, Ao);
  gemm_nt<2><<<gg, blk, 0, stream>>>(Ao, Wob, d_out, M, N, K);
}

// Round 4
// 384.418 us; speedup vs baseline: 1.1219x; 1.1219x over previous
//
#include <hip/hip_runtime.h>

typedef unsigned short u16;
typedef unsigned int u32;
typedef __attribute__((ext_vector_type(8))) short bf16x8;   // 8 bf16 = 4 VGPRs
typedef __attribute__((ext_vector_type(4))) float f32x4;

#define MFMA16(A, B, C) __builtin_amdgcn_mfma_f32_16x16x32_bf16(A, B, C, 0, 0, 0)

__device__ __forceinline__ u16 f2bf(float f) {
  union { float f; unsigned u; } x; x.f = f;
  unsigned r = x.u + 0x7fffu + ((x.u >> 16) & 1u);   // RNE
  return (u16)(r >> 16);
}

// async global->LDS, 16B per lane; LDS dest is wave-uniform base + lane*16
// (m97 pattern: lane-linear LDS layout, no padding).
__device__ __forceinline__ void gload_lds16(const u16* g, u16* l) {
  __builtin_amdgcn_global_load_lds((const __attribute__((address_space(1))) void*)g,
                                   (__attribute__((address_space(3))) void*)l,
                                   16, 0, 0);
}

// ---------------------------------------------------------------------------
// One conversion kernel: fp32 -> bf16 for x, Wq|Wk|Wv (concatenated into
// Wqkvb for the fused QKV GEMM), and Wo. 8 elems/thread.
// ---------------------------------------------------------------------------
__global__ __launch_bounds__(256) void cvt_all(const float* __restrict__ x,
                                               const float* __restrict__ Wq,
                                               const float* __restrict__ Wk,
                                               const float* __restrict__ Wv,
                                               const float* __restrict__ Wo,
                                               u16* __restrict__ xb,
                                               u16* __restrict__ Wqkvb,
                                               u16* __restrict__ Wob,
                                               int NE, int NW) {
  const int e = (blockIdx.x * 256 + threadIdx.x) * 8;
  const float* s;
  u16* d;
  if (e < NE) { s = x + e; d = xb + e; }
  else {
    int f = e - NE;
    if (f < 3 * NW) {
      d = Wqkvb + f;
      s = (f < NW) ? Wq + f : (f < 2 * NW) ? Wk + (f - NW) : Wv + (f - 2 * NW);
    } else { f -= 3 * NW; s = Wo + f; d = Wob + f; }
  }
  const float4 a = *(const float4*)s;
  const float4 b = *(const float4*)(s + 4);
  bf16x8 o;
  o[0] = (short)f2bf(a.x); o[1] = (short)f2bf(a.y);
  o[2] = (short)f2bf(a.z); o[3] = (short)f2bf(a.w);
  o[4] = (short)f2bf(b.x); o[5] = (short)f2bf(b.y);
  o[6] = (short)f2bf(b.z); o[7] = (short)f2bf(b.w);
  *(bf16x8*)d = o;
}

// mask [2][2048] int32 -> bit-packed words mbits[2][64] (bit j of word w =
// mask[b][w*32+j]). One scalar load per 32 keys in the attention loop.
__global__ void pack_mask(const int* __restrict__ mask, u32* __restrict__ mbits) {
  const int t = blockIdx.x * blockDim.x + threadIdx.x;
  if (t >= 128) return;
  const int* m = mask + t * 32;
  u32 w = 0;
#pragma unroll
  for (int j = 0; j < 32; j++) w |= (m[j] != 0 ? 1u : 0u) << j;
  mbits[t] = w;
}

// ---------------------------------------------------------------------------
// NT GEMM: C = A[M,K] @ B[N,K]^T, bf16 in, fp32 accum, m97-style staging:
// 128x128 tile, BK=32, unpadded stride-32 LDS filled by global_load_lds x16.
// MODE 0: fp32 out row-major into C0 (final output).
// MODE 1: fused QKV (N=3072): col<1024 -> C0 (Q, bf16 row-major),
//         col<2048 -> C1 (K), else C2 = per-head-transposed V:
//         Vt[((row>>11)*1024 + n)*2048 + (row&2047)], n = col-2048.
// ---------------------------------------------------------------------------
template <int MODE>
__global__ __launch_bounds__(256) void gemm_nt(const u16* __restrict__ A,
                                               const u16* __restrict__ B,
                                               void* __restrict__ C0,
                                               void* __restrict__ C1,
                                               void* __restrict__ C2,
                                               int M, int N, int K) {
  __shared__ alignas(16) u16 As[128 * 32];   // lane-linear: chunk l -> elems l*8
  __shared__ alignas(16) u16 Bs[128 * 32];
  const int t = threadIdx.x;
  const int lane = t & 63, wave = t >> 6;
  const int quad = lane >> 4, l16 = lane & 15;
  const int m0 = blockIdx.y * 128, n0 = blockIdx.x * 128;
  const int wm = (wave >> 1) * 64, wn = (wave & 1) * 64;

  f32x4 acc[4][4] = {};

  for (int kk = 0; kk < K; kk += 32) {
#pragma unroll
    for (int i = 0; i < 2; i++) {
      const int l = t + i * 256;            // chunk id; LDS offset = l*16 bytes
      const int row = l >> 2, c8 = (l & 3) * 8;
      gload_lds16(A + (size_t)(m0 + row) * K + kk + c8, As + (size_t)l * 8);
      gload_lds16(B + (size_t)(n0 + row) * K + kk + c8, Bs + (size_t)l * 8);
    }
    __syncthreads();   // drains vmcnt(0) then barrier

    bf16x8 af[4], bfr[4];
#pragma unroll
    for (int i = 0; i < 4; i++)
      af[i] = *(const bf16x8*)(As + (wm + i * 16 + l16) * 32 + quad * 8);
#pragma unroll
    for (int j = 0; j < 4; j++)
      bfr[j] = *(const bf16x8*)(Bs + (wn + j * 16 + l16) * 32 + quad * 8);
#pragma unroll
    for (int i = 0; i < 4; i++)
#pragma unroll
      for (int j = 0; j < 4; j++)
        acc[i][j] = MFMA16(af[i], bfr[j], acc[i][j]);
    __syncthreads();
  }

  // C/D layout: col = lane&15, row = quad*4 + r  [m89/m91 verified]
#pragma unroll
  for (int i = 0; i < 4; i++)
#pragma unroll
    for (int j = 0; j < 4; j++)
#pragma unroll
      for (int r = 0; r < 4; r++) {
        const int row = m0 + wm + i * 16 + quad * 4 + r;
        const int col = n0 + wn + j * 16 + l16;
        const float v = acc[i][j][r];
        if (MODE == 0) {
          ((float*)C0)[(size_t)row * N + col] = v;
        } else {
          if (col < 1024)
            ((u16*)C0)[(size_t)row * 1024 + col] = f2bf(v);
          else if (col < 2048)
            ((u16*)C1)[(size_t)row * 1024 + (col - 1024)] = f2bf(v);
          else
            ((u16*)C2)[((size_t)(row >> 11) * 1024 + (col - 2048)) * 2048 +
                       (row & 2047)] = f2bf(v);
        }
      }
}

// ---------------------------------------------------------------------------
// Flash attention, deferred softmax (fixed max): p = exp2((v-8)*log2e),
// per-lane partial row-sums, ONE cross-lane reduction at the end, no accO
// rescale, no block barriers (intra-wave LDS round-trip w/ lgkmcnt waits).
// One block = 64 q x (b,h); 4 independent waves, each owns 16 q rows.
// ---------------------------------------------------------------------------
__global__ __launch_bounds__(256) void attn_fwd(const u16* __restrict__ Q,
                                                const u16* __restrict__ Kb_,
                                                const u16* __restrict__ Vt,
                                                const u32* __restrict__ mbits,
                                                u16* __restrict__ O) {
  constexpr int S = 2048, E = 1024, D = 64;
  __shared__ alignas(16) u16 Pl[2][4][16 * 40];   // double-buffered per-wave P
  const int t = threadIdx.x;
  const int lane = t & 63, wave = t >> 6;
  const int quad = lane >> 4, l16 = lane & 15;
  const int bh = blockIdx.y, b = bh >> 4, h = bh & 15;
  const int q0 = blockIdx.x * 64 + wave * 16;

  const u16* qp = Q + ((size_t)(b * S) + q0 + l16) * E + h * D;
  const bf16x8 aq0 = *(const bf16x8*)(qp + quad * 8);
  const bf16x8 aq1 = *(const bf16x8*)(qp + 32 + quad * 8);

  const u16* kbase = Kb_ + (size_t)(b * S) * E + h * D;
  const u16* vbase = Vt + (size_t)(b * 16 + h) * D * S;
  const u32* mb = mbits + b * 64;

  float lr[4] = {0.f, 0.f, 0.f, 0.f};
  f32x4 accO[4] = {};
  int qr[4];
#pragma unroll
  for (int r = 0; r < 4; r++) qr[r] = q0 + quad * 4 + r - 2047;

  const float K1 = 0.125f * 1.44269504f;           // score scale * log2e
  const float K2 = 2.44140625e-4f * 1.44269504f;   // (alpha/S) * log2e
  const float K3 = -8.0f * 1.44269504f;            // fixed-max shift

  for (int kc = 0; kc < S; kc += 32) {
    const u16* kp0 = kbase + (size_t)(kc + l16) * E;
    const u16* kp1 = kp0 + 16 * E;
    bf16x8 bk00 = *(const bf16x8*)(kp0 + quad * 8);
    bf16x8 bk01 = *(const bf16x8*)(kp0 + 32 + quad * 8);
    bf16x8 bk10 = *(const bf16x8*)(kp1 + quad * 8);
    bf16x8 bk11 = *(const bf16x8*)(kp1 + 32 + quad * 8);
    f32x4 s0 = {}, s1 = {};
    s0 = MFMA16(aq0, bk00, s0);
    s0 = MFMA16(aq1, bk01, s0);
    s1 = MFMA16(aq0, bk10, s1);
    s1 = MFMA16(aq1, bk11, s1);

    const u32 mw = mb[kc >> 5];
    const int k0 = kc + l16;
    u16* pl = Pl[(kc >> 5) & 1][wave];

#pragma unroll
    for (int r = 0; r < 4; r++) {
      const float d0 = fabsf((float)(k0 + qr[r]));
      const float d1 = fabsf((float)(k0 + 16 + qr[r]));
      const float e0 = fmaf(d0, -K2, fmaf(s0[r], K1, K3));
      const float e1 = fmaf(d1, -K2, fmaf(s1[r], K1, K3));
      float p0 = __builtin_exp2f(e0);
      float p1 = __builtin_exp2f(e1);
      p0 = ((mw >> l16) & 1u) ? 0.f : p0;
      p1 = ((mw >> (l16 + 16)) & 1u) ? 0.f : p1;
      lr[r] += p0 + p1;
      pl[(quad * 4 + r) * 40 + l16] = f2bf(p0);
      pl[(quad * 4 + r) * 40 + l16 + 16] = f2bf(p1);
    }
    // intra-wave visibility: drain DS writes, block compiler reordering
    asm volatile("s_waitcnt lgkmcnt(0)" ::: "memory");
    const bf16x8 ap = *(const bf16x8*)(pl + l16 * 40 + quad * 8);
#pragma unroll
    for (int tt = 0; tt < 4; tt++) {
      bf16x8 bv = *(const bf16x8*)(vbase + (size_t)(tt * 16 + l16) * S + kc + quad * 8);
      accO[tt] = MFMA16(ap, bv, accO[tt]);
    }
  }

#pragma unroll
  for (int r = 0; r < 4; r++) {
    float l = lr[r];                     // partial over this lane's 2 cols/chunk
    l += __shfl_xor(l, 1);
    l += __shfl_xor(l, 2);
    l += __shfl_xor(l, 4);
    l += __shfl_xor(l, 8);               // sum across the 16-lane row group
    const float inv = 1.0f / l;
    const int qg = q0 + quad * 4 + r;
#pragma unroll
    for (int tt = 0; tt < 4; tt++)
      O[((size_t)(b * S) + qg) * E + h * D + tt * 16 + l16] =
          f2bf(accO[tt][r] * inv);
  }
}

// ---------------------------------------------------------------------------
extern "C" void kernel_launch(void* const* d_in, const int* in_sizes, int n_in,
                              void* d_out, int out_size, void* d_ws, size_t ws_size,
                              hipStream_t stream) {
  const float* x  = (const float*)d_in[0];
  const float* Wq = (const float*)d_in[1];
  const float* Wk = (const float*)d_in[2];
  const float* Wv = (const float*)d_in[3];
  const float* Wo = (const float*)d_in[4];
  const int* mask = (const int*)d_in[5];

  const int M = 4096, N = 1024, K = 1024;    // M = B*S
  const int NE = M * N;                      // 4,194,304
  const int NW = N * K;                      // 1,048,576

  u16* xb    = (u16*)d_ws;
  u16* Wqkvb = xb + NE;                      // [3072,1024] concat q|k|v
  u16* Wob   = Wqkvb + (size_t)3 * NW;
  u16* Qb    = Wob + NW;                     // [4096,1024] bf16
  u16* Kb    = Qb + NE;
  u16* Vt    = Kb + NE;                      // [B*H, 64, 2048] transposed
  u16* Ao    = Vt + NE;                      // attention out [4096,1024]
  u32* mbits = (u32*)(Ao + NE);              // 128 words

  dim3 blk(256);
  cvt_all<<<(NE + 4 * NW) / 2048, blk, 0, stream>>>(x, Wq, Wk, Wv, Wo,
                                                    xb, Wqkvb, Wob, NE, NW);
  pack_mask<<<1, 128, 0, stream>>>(mask, mbits);

  gemm_nt<1><<<dim3(3072 / 128, M / 128), blk, 0, stream>>>(
      xb, Wqkvb, Qb, Kb, Vt, M, 3072, K);
  attn_fwd<<<dim3(32, 32), blk, 0, stream>>>(Qb, Kb, Vt, mbits, Ao);
  gemm_nt<0><<<dim3(N / 128, M / 128), blk, 0, stream>>>(
      Ao, Wob, d_out, nullptr, nullptr, M, N, K);
}

// Round 5
// 247.578 us; speedup vs baseline: 1.7420x; 1.5527x over previous
//
#include <hip/hip_runtime.h>

typedef unsigned short u16;
typedef unsigned int u32;
typedef __attribute__((ext_vector_type(8))) short bf16x8;   // 8 bf16 = 4 VGPRs
typedef __attribute__((ext_vector_type(4))) float f32x4;

#define MFMA16(A, B, C) __builtin_amdgcn_mfma_f32_16x16x32_bf16(A, B, C, 0, 0, 0)

__device__ __forceinline__ u16 f2bf(float f) {
  union { float f; unsigned u; } x; x.f = f;
  unsigned r = x.u + 0x7fffu + ((x.u >> 16) & 1u);   // RNE
  return (u16)(r >> 16);
}

// async global->LDS, 16B/lane; LDS dest is wave-uniform base + lane*16.
__device__ __forceinline__ void gload_lds16(const u16* g, u16* l) {
  __builtin_amdgcn_global_load_lds((const __attribute__((address_space(1))) void*)g,
                                   (__attribute__((address_space(3))) void*)l,
                                   16, 0, 0);
}

// ---------------------------------------------------------------------------
// fp32 -> bf16 for x, Wq|Wk|Wv (concat -> Wqkvb), Wo. 8 elems/thread.
// ---------------------------------------------------------------------------
__global__ __launch_bounds__(256) void cvt_all(const float* __restrict__ x,
                                               const float* __restrict__ Wq,
                                               const float* __restrict__ Wk,
                                               const float* __restrict__ Wv,
                                               const float* __restrict__ Wo,
                                               u16* __restrict__ xb,
                                               u16* __restrict__ Wqkvb,
                                               u16* __restrict__ Wob,
                                               int NE, int NW) {
  const int e = (blockIdx.x * 256 + threadIdx.x) * 8;
  const float* s;
  u16* d;
  if (e < NE) { s = x + e; d = xb + e; }
  else {
    int f = e - NE;
    if (f < 3 * NW) {
      d = Wqkvb + f;
      s = (f < NW) ? Wq + f : (f < 2 * NW) ? Wk + (f - NW) : Wv + (f - 2 * NW);
    } else { f -= 3 * NW; s = Wo + f; d = Wob + f; }
  }
  const float4 a = *(const float4*)s;
  const float4 b = *(const float4*)(s + 4);
  bf16x8 o;
  o[0] = (short)f2bf(a.x); o[1] = (short)f2bf(a.y);
  o[2] = (short)f2bf(a.z); o[3] = (short)f2bf(a.w);
  o[4] = (short)f2bf(b.x); o[5] = (short)f2bf(b.y);
  o[6] = (short)f2bf(b.z); o[7] = (short)f2bf(b.w);
  *(bf16x8*)d = o;
}

__global__ void pack_mask(const int* __restrict__ mask, u32* __restrict__ mbits) {
  const int t = blockIdx.x * blockDim.x + threadIdx.x;
  if (t >= 128) return;
  const int* m = mask + t * 32;
  u32 w = 0;
#pragma unroll
  for (int j = 0; j < 32; j++) w |= (m[j] != 0 ? 1u : 0u) << j;
  mbits[t] = w;
}

// ---------------------------------------------------------------------------
// NT GEMM (unchanged from round 4): 128x128 tile, BK=32, global_load_lds x16.
// MODE 0: fp32 out row-major. MODE 1: fused QKV split-store (Q,K,Vt).
// ---------------------------------------------------------------------------
template <int MODE>
__global__ __launch_bounds__(256) void gemm_nt(const u16* __restrict__ A,
                                               const u16* __restrict__ B,
                                               void* __restrict__ C0,
                                               void* __restrict__ C1,
                                               void* __restrict__ C2,
                                               int M, int N, int K) {
  __shared__ alignas(16) u16 As[128 * 32];
  __shared__ alignas(16) u16 Bs[128 * 32];
  const int t = threadIdx.x;
  const int lane = t & 63, wave = t >> 6;
  const int quad = lane >> 4, l16 = lane & 15;
  const int m0 = blockIdx.y * 128, n0 = blockIdx.x * 128;
  const int wm = (wave >> 1) * 64, wn = (wave & 1) * 64;

  f32x4 acc[4][4] = {};

  for (int kk = 0; kk < K; kk += 32) {
#pragma unroll
    for (int i = 0; i < 2; i++) {
      const int l = t + i * 256;
      const int row = l >> 2, c8 = (l & 3) * 8;
      gload_lds16(A + (size_t)(m0 + row) * K + kk + c8, As + (size_t)l * 8);
      gload_lds16(B + (size_t)(n0 + row) * K + kk + c8, Bs + (size_t)l * 8);
    }
    __syncthreads();

    bf16x8 af[4], bfr[4];
#pragma unroll
    for (int i = 0; i < 4; i++)
      af[i] = *(const bf16x8*)(As + (wm + i * 16 + l16) * 32 + quad * 8);
#pragma unroll
    for (int j = 0; j < 4; j++)
      bfr[j] = *(const bf16x8*)(Bs + (wn + j * 16 + l16) * 32 + quad * 8);
#pragma unroll
    for (int i = 0; i < 4; i++)
#pragma unroll
      for (int j = 0; j < 4; j++)
        acc[i][j] = MFMA16(af[i], bfr[j], acc[i][j]);
    __syncthreads();
  }

#pragma unroll
  for (int i = 0; i < 4; i++)
#pragma unroll
    for (int j = 0; j < 4; j++)
#pragma unroll
      for (int r = 0; r < 4; r++) {
        const int row = m0 + wm + i * 16 + quad * 4 + r;
        const int col = n0 + wn + j * 16 + l16;
        const float v = acc[i][j][r];
        if (MODE == 0) {
          ((float*)C0)[(size_t)row * N + col] = v;
        } else {
          if (col < 1024)
            ((u16*)C0)[(size_t)row * 1024 + col] = f2bf(v);
          else if (col < 2048)
            ((u16*)C1)[(size_t)row * 1024 + (col - 1024)] = f2bf(v);
          else
            ((u16*)C2)[((size_t)(row >> 11) * 1024 + (col - 2048)) * 2048 +
                       (row & 2047)] = f2bf(v);
        }
      }
}

// ---------------------------------------------------------------------------
// Flash attention v3: block-cooperative double-buffered K/V staging via
// global_load_lds (XOR-swizzled source-chunk placement, lane-linear dest),
// deferred softmax, V frags read from LDS BEFORE the P clobber.
// Block = 64 q x (b,h); 4 waves, each owns 16 q rows. 32-key chunks.
// ---------------------------------------------------------------------------
__global__ __launch_bounds__(256) void attn_fwd(const u16* __restrict__ Q,
                                                const u16* __restrict__ Kb_,
                                                const u16* __restrict__ Vt,
                                                const u32* __restrict__ mbits,
                                                u16* __restrict__ O) {
  constexpr int S = 2048, E = 1024, D = 64;
  __shared__ alignas(16) u16 Ks[2][32 * 64];   // [buf][key][d]   4 KB each
  __shared__ alignas(16) u16 Vs[2][64 * 32];   // [buf][d][key]   4 KB each
  __shared__ alignas(16) u16 Pl[4][16 * 40];   // per-wave P tile
  const int t = threadIdx.x;
  const int lane = t & 63, wave = t >> 6;
  const int quad = lane >> 4, l16 = lane & 15;
  const int bh = blockIdx.y, b = bh >> 4, h = bh & 15;
  const int q0 = blockIdx.x * 64 + wave * 16;

  // staging indices (per thread, fixed): K: 32 rows x 8 chunks; V: 64 x 4
  const int krow = t >> 3, kc8 = t & 7, ksc = kc8 ^ (krow & 7);
  const int vrow = t >> 2, vc4 = t & 3, vsc = vc4 ^ (vrow & 3);
  const u16* kg = Kb_ + (size_t)(b * S + krow) * E + h * 64 + ksc * 8;
  const u16* vg = Vt + (size_t)(b * 16 + h) * D * S + (size_t)vrow * S + vsc * 8;

  const u16* qp = Q + ((size_t)(b * S) + q0 + l16) * E + h * D;
  const bf16x8 aq0 = *(const bf16x8*)(qp + quad * 8);
  const bf16x8 aq1 = *(const bf16x8*)(qp + 32 + quad * 8);

  const u32* mb = mbits + b * 64;
  u16* pl = Pl[wave];

  float lr[4] = {0.f, 0.f, 0.f, 0.f};
  f32x4 accO[4] = {};
  int qr[4];
#pragma unroll
  for (int r = 0; r < 4; r++) qr[r] = q0 + quad * 4 + r - 2047;

  const float K1 = 0.125f * 1.44269504f;
  const float K2 = 2.44140625e-4f * 1.44269504f;
  const float K3 = -8.0f * 1.44269504f;

  // swizzled read offsets (u16 units)
  const int sxk = l16 & 7;                       // K-tile row swizzle key
  const int kofs_lo = l16 * 64 + ((quad ^ sxk)) * 8;        // d 0..31
  const int kofs_hi = l16 * 64 + (((4 + quad) ^ sxk)) * 8;  // d 32..63

  // initial stage of chunk 0 into buf 0
  gload_lds16(kg, Ks[0] + (size_t)t * 8);
  gload_lds16(vg, Vs[0] + (size_t)t * 8);
  __syncthreads();

  int buf = 0;
  for (int kc = 0; kc < S; kc += 32) {
    if (kc + 32 < S) {   // prefetch next chunk into other buffer (in flight
      gload_lds16(kg + (size_t)(kc + 32) * E, Ks[buf ^ 1] + (size_t)t * 8);
      gload_lds16(vg + (kc + 32), Vs[buf ^ 1] + (size_t)t * 8);
    }

    const u16* ks = Ks[buf];
    const u16* vs = Vs[buf];
    // K B-frags (key tiles 0,1 x d-halves)
    bf16x8 bk00 = *(const bf16x8*)(ks + kofs_lo);
    bf16x8 bk01 = *(const bf16x8*)(ks + kofs_hi);
    bf16x8 bk10 = *(const bf16x8*)(ks + 16 * 64 + kofs_lo);
    bf16x8 bk11 = *(const bf16x8*)(ks + 16 * 64 + kofs_hi);
    // V B-frags — read BEFORE the P clobber so they never sit in the chain
    bf16x8 bv[4];
#pragma unroll
    for (int tt = 0; tt < 4; tt++) {
      const int d = tt * 16 + l16;
      bv[tt] = *(const bf16x8*)(vs + d * 32 + ((quad ^ (l16 & 3))) * 8);
    }

    f32x4 s0 = {}, s1 = {};
    s0 = MFMA16(aq0, bk00, s0);
    s0 = MFMA16(aq1, bk01, s0);
    s1 = MFMA16(aq0, bk10, s1);
    s1 = MFMA16(aq1, bk11, s1);

    const u32 mw = mb[kc >> 5];
    const int k0 = kc + l16;

#pragma unroll
    for (int r = 0; r < 4; r++) {
      const float d0 = fabsf((float)(k0 + qr[r]));
      const float d1 = fabsf((float)(k0 + 16 + qr[r]));
      const float e0 = fmaf(d0, -K2, fmaf(s0[r], K1, K3));
      const float e1 = fmaf(d1, -K2, fmaf(s1[r], K1, K3));
      float p0 = __builtin_exp2f(e0);
      float p1 = __builtin_exp2f(e1);
      p0 = ((mw >> l16) & 1u) ? 0.f : p0;
      p1 = ((mw >> (l16 + 16)) & 1u) ? 0.f : p1;
      lr[r] += p0 + p1;
      pl[(quad * 4 + r) * 40 + l16] = f2bf(p0);
      pl[(quad * 4 + r) * 40 + l16 + 16] = f2bf(p1);
    }
    // cross-lane P visibility (intra-wave): drain DS, stop reordering
    asm volatile("s_waitcnt lgkmcnt(0)" ::: "memory");
    const bf16x8 ap = *(const bf16x8*)(pl + l16 * 40 + quad * 8);
#pragma unroll
    for (int tt = 0; tt < 4; tt++) accO[tt] = MFMA16(ap, bv[tt], accO[tt]);

    __syncthreads();   // drain prefetch (vmcnt) + protect staging buffers
    buf ^= 1;
  }

#pragma unroll
  for (int r = 0; r < 4; r++) {
    float l = lr[r];
    l += __shfl_xor(l, 1);
    l += __shfl_xor(l, 2);
    l += __shfl_xor(l, 4);
    l += __shfl_xor(l, 8);
    const float inv = 1.0f / l;
    const int qg = q0 + quad * 4 + r;
#pragma unroll
    for (int tt = 0; tt < 4; tt++)
      O[((size_t)(b * S) + qg) * E + h * D + tt * 16 + l16] =
          f2bf(accO[tt][r] * inv);
  }
}

// ---------------------------------------------------------------------------
extern "C" void kernel_launch(void* const* d_in, const int* in_sizes, int n_in,
                              void* d_out, int out_size, void* d_ws, size_t ws_size,
                              hipStream_t stream) {
  const float* x  = (const float*)d_in[0];
  const float* Wq = (const float*)d_in[1];
  const float* Wk = (const float*)d_in[2];
  const float* Wv = (const float*)d_in[3];
  const float* Wo = (const float*)d_in[4];
  const int* mask = (const int*)d_in[5];

  const int M = 4096, N = 1024, K = 1024;
  const int NE = M * N, NW = N * K;

  u16* xb    = (u16*)d_ws;
  u16* Wqkvb = xb + NE;
  u16* Wob   = Wqkvb + (size_t)3 * NW;
  u16* Qb    = Wob + NW;
  u16* Kb    = Qb + NE;
  u16* Vt    = Kb + NE;
  u16* Ao    = Vt + NE;
  u32* mbits = (u32*)(Ao + NE);

  dim3 blk(256);
  cvt_all<<<(NE + 4 * NW) / 2048, blk, 0, stream>>>(x, Wq, Wk, Wv, Wo,
                                                    xb, Wqkvb, Wob, NE, NW);
  pack_mask<<<1, 128, 0, stream>>>(mask, mbits);

  gemm_nt<1><<<dim3(3072 / 128, M / 128), blk, 0, stream>>>(
      xb, Wqkvb, Qb, Kb, Vt, M, 3072, K);
  attn_fwd<<<dim3(32, 32), blk, 0, stream>>>(Qb, Kb, Vt, mbits, Ao);
  gemm_nt<0><<<dim3(N / 128, M / 128), blk, 0, stream>>>(
      Ao, Wob, d_out, nullptr, nullptr, M, N, K);
}

// Round 6
// 237.135 us; speedup vs baseline: 1.8187x; 1.0440x over previous
//
#include <hip/hip_runtime.h>

typedef unsigned short u16;
typedef unsigned int u32;
typedef unsigned long long u64;
typedef __attribute__((ext_vector_type(8))) short bf16x8;   // 8 bf16 = 4 VGPRs
typedef __attribute__((ext_vector_type(4))) float f32x4;

#define MFMA16(A, B, C) __builtin_amdgcn_mfma_f32_16x16x32_bf16(A, B, C, 0, 0, 0)

__device__ __forceinline__ u16 f2bf(float f) {
  union { float f; unsigned u; } x; x.f = f;
  unsigned r = x.u + 0x7fffu + ((x.u >> 16) & 1u);   // RNE
  return (u16)(r >> 16);
}

// pack two fp32 -> two bf16 in one dword (round-half-up): lo16=a, hi16=b
__device__ __forceinline__ u32 pack_bf2(float a, float b) {
  const u32 ua = __builtin_bit_cast(u32, a) + 0x8000u;
  const u32 ub = __builtin_bit_cast(u32, b) + 0x8000u;
  return __builtin_amdgcn_perm(ub, ua, 0x07060302u);  // bytes: [a2,a3,b2,b3]
}

// async global->LDS, 16B/lane; LDS dest must be lane-linear (wave base + lane*16)
__device__ __forceinline__ void gload_lds16(const u16* g, u16* l) {
  __builtin_amdgcn_global_load_lds((const __attribute__((address_space(1))) void*)g,
                                   (__attribute__((address_space(3))) void*)l,
                                   16, 0, 0);
}

// ---------------------------------------------------------------------------
// fp32 -> bf16 for x, Wq|Wk|Wv (concat -> Wqkvb), Wo. 8 elems/thread.
// ---------------------------------------------------------------------------
__global__ __launch_bounds__(256) void cvt_all(const float* __restrict__ x,
                                               const float* __restrict__ Wq,
                                               const float* __restrict__ Wk,
                                               const float* __restrict__ Wv,
                                               const float* __restrict__ Wo,
                                               u16* __restrict__ xb,
                                               u16* __restrict__ Wqkvb,
                                               u16* __restrict__ Wob,
                                               int NE, int NW) {
  const int e = (blockIdx.x * 256 + threadIdx.x) * 8;
  const float* s;
  u16* d;
  if (e < NE) { s = x + e; d = xb + e; }
  else {
    int f = e - NE;
    if (f < 3 * NW) {
      d = Wqkvb + f;
      s = (f < NW) ? Wq + f : (f < 2 * NW) ? Wk + (f - NW) : Wv + (f - 2 * NW);
    } else { f -= 3 * NW; s = Wo + f; d = Wob + f; }
  }
  const float4 a = *(const float4*)s;
  const float4 b = *(const float4*)(s + 4);
  bf16x8 o;
  o[0] = (short)f2bf(a.x); o[1] = (short)f2bf(a.y);
  o[2] = (short)f2bf(a.z); o[3] = (short)f2bf(a.w);
  o[4] = (short)f2bf(b.x); o[5] = (short)f2bf(b.y);
  o[6] = (short)f2bf(b.z); o[7] = (short)f2bf(b.w);
  *(bf16x8*)d = o;
}

__global__ void pack_mask(const int* __restrict__ mask, u32* __restrict__ mbits) {
  const int t = blockIdx.x * blockDim.x + threadIdx.x;
  if (t >= 128) return;
  const int* m = mask + t * 32;
  u32 w = 0;
#pragma unroll
  for (int j = 0; j < 32; j++) w |= (m[j] != 0 ? 1u : 0u) << j;
  mbits[t] = w;
}

// ---------------------------------------------------------------------------
// NT GEMM: 128x128 tile, BK=32, global_load_lds x16 staging.
// MODE 0: fp32 out row-major.
// MODE 1: fused QKV. Q,K bf16 row-major. V -> per-head-transposed Vt with
//   keys PAIR-INTERLEAVED within each 32-group: pos = g*32 + 2*(s&15) + ((s>>4)&1).
//   Lane packs (key s, key s+16) = (i, i+1) accs into one b32 store.
// ---------------------------------------------------------------------------
template <int MODE>
__global__ __launch_bounds__(256) void gemm_nt(const u16* __restrict__ A,
                                               const u16* __restrict__ B,
                                               void* __restrict__ C0,
                                               void* __restrict__ C1,
                                               void* __restrict__ C2,
                                               int M, int N, int K) {
  __shared__ alignas(16) u16 As[128 * 32];
  __shared__ alignas(16) u16 Bs[128 * 32];
  const int t = threadIdx.x;
  const int lane = t & 63, wave = t >> 6;
  const int quad = lane >> 4, l16 = lane & 15;
  const int m0 = blockIdx.y * 128, n0 = blockIdx.x * 128;
  const int wm = (wave >> 1) * 64, wn = (wave & 1) * 64;

  f32x4 acc[4][4] = {};

  for (int kk = 0; kk < K; kk += 32) {
#pragma unroll
    for (int i = 0; i < 2; i++) {
      const int l = t + i * 256;
      const int row = l >> 2, c8 = (l & 3) * 8;
      gload_lds16(A + (size_t)(m0 + row) * K + kk + c8, As + (size_t)l * 8);
      gload_lds16(B + (size_t)(n0 + row) * K + kk + c8, Bs + (size_t)l * 8);
    }
    __syncthreads();

    bf16x8 af[4], bfr[4];
#pragma unroll
    for (int i = 0; i < 4; i++)
      af[i] = *(const bf16x8*)(As + (wm + i * 16 + l16) * 32 + quad * 8);
#pragma unroll
    for (int j = 0; j < 4; j++)
      bfr[j] = *(const bf16x8*)(Bs + (wn + j * 16 + l16) * 32 + quad * 8);
#pragma unroll
    for (int i = 0; i < 4; i++)
#pragma unroll
      for (int j = 0; j < 4; j++)
        acc[i][j] = MFMA16(af[i], bfr[j], acc[i][j]);
    __syncthreads();
  }

  // C/D layout: col = lane&15, row = quad*4 + r  [m89/m91 verified]
#pragma unroll
  for (int j = 0; j < 4; j++) {
    const int col = n0 + wn + j * 16 + l16;
    if (MODE == 0) {
#pragma unroll
      for (int i = 0; i < 4; i++)
#pragma unroll
        for (int r = 0; r < 4; r++)
          ((float*)C0)[(size_t)(m0 + wm + i * 16 + quad * 4 + r) * N + col] =
              acc[i][j][r];
    } else if (col < 1024) {
#pragma unroll
      for (int i = 0; i < 4; i++)
#pragma unroll
        for (int r = 0; r < 4; r++)
          ((u16*)C0)[(size_t)(m0 + wm + i * 16 + quad * 4 + r) * 1024 + col] =
              f2bf(acc[i][j][r]);
    } else if (col < 2048) {
#pragma unroll
      for (int i = 0; i < 4; i++)
#pragma unroll
        for (int r = 0; r < 4; r++)
          ((u16*)C1)[(size_t)(m0 + wm + i * 16 + quad * 4 + r) * 1024 +
                     (col - 1024)] = f2bf(acc[i][j][r]);
    } else {
      // Vt: rows 16-apart (i, i+1) are group-pair -> adjacent interleaved pos
      u16* base = (u16*)C2 +
                  ((size_t)(m0 >> 11) * 1024 + (col - 2048)) * 2048;
#pragma unroll
      for (int i = 0; i < 4; i += 2)
#pragma unroll
        for (int r = 0; r < 4; r++) {
          const int s0 = m0 + wm + i * 16 + quad * 4 + r;   // parity-0 key
          const int pos = ((s0 & 2047) >> 5) * 32 + 2 * (s0 & 15);
          *(u32*)(base + pos) = pack_bf2(acc[i][j][r], acc[i + 1][j][r]);
        }
    }
  }
}

// ---------------------------------------------------------------------------
// Flash attention v4: 4 waves x 32 q = 128 q per block x (b,h); 64-key chunks;
// block-cooperative double-buffered K/V LDS staging (source-chunk XOR swizzle,
// lane-linear dest); deferred softmax; pair-interleaved P stored as b32;
// K/V frags reused across the wave's 2 q-tiles.
// ---------------------------------------------------------------------------
__global__ __launch_bounds__(256) void attn_fwd(const u16* __restrict__ Q,
                                                const u16* __restrict__ Kb_,
                                                const u16* __restrict__ Vt,
                                                const u32* __restrict__ mbits,
                                                u16* __restrict__ O) {
  constexpr int S = 2048, E = 1024;
  __shared__ alignas(16) u16 Ks[2][64 * 64];   // [buf][key][d]        8 KB
  __shared__ alignas(16) u16 Vs[2][64 * 64];   // [buf][d][pos]        8 KB
  __shared__ alignas(16) u16 Pl[4][32 * 72];   // per-wave P, stride 72
  const int t = threadIdx.x;
  const int lane = t & 63, wave = t >> 6;
  const int quad = lane >> 4, l16 = lane & 15;
  const int bh = blockIdx.y, b = bh >> 4, h = bh & 15;
  const int q0 = blockIdx.x * 128 + wave * 32;

  // staging: 512 x 16B chunks per tile, 2 per thread; XOR-swizzled source col
  const int c0 = t, c1 = t + 256;
  const int kr0 = c0 >> 3, kr1 = c1 >> 3;
  const int kcol0 = ((c0 & 7) ^ (kr0 & 7)) * 8;
  const int kcol1 = ((c1 & 7) ^ (kr1 & 7)) * 8;
  const u16* kP0 = Kb_ + (size_t)(b * S + kr0) * E + h * 64 + kcol0;
  const u16* kP1 = Kb_ + (size_t)(b * S + kr1) * E + h * 64 + kcol1;
  const u16* vbase = Vt + (size_t)(b * 16 + h) * 64 * S;
  const u16* vP0 = vbase + (size_t)kr0 * S + kcol0;
  const u16* vP1 = vbase + (size_t)kr1 * S + kcol1;

  // Q A-frags: 2 q-tiles x 2 d-halves, register-resident
  bf16x8 aq[2][2];
#pragma unroll
  for (int qt = 0; qt < 2; qt++) {
    const u16* qp = Q + ((size_t)(b * S) + q0 + qt * 16 + l16) * E + h * 64;
    aq[qt][0] = *(const bf16x8*)(qp + quad * 8);
    aq[qt][1] = *(const bf16x8*)(qp + 32 + quad * 8);
  }

  const u32* mb = mbits + b * 64;
  const int sx = l16 & 7;

  float lr[2][4] = {};
  f32x4 accO[2][4] = {};
  float fq[2][4];
#pragma unroll
  for (int qt = 0; qt < 2; qt++)
#pragma unroll
    for (int r = 0; r < 4; r++)
      fq[qt][r] = (float)(q0 + qt * 16 + quad * 4 + r - 2047);

  const float K1 = 0.125f * 1.44269504f;
  const float K2 = 2.44140625e-4f * 1.44269504f;
  const float K3 = -8.0f * 1.44269504f;

  // stage chunk 0 -> buf 0
  gload_lds16(kP0, Ks[0] + c0 * 8);
  gload_lds16(kP1, Ks[0] + c1 * 8);
  gload_lds16(vP0, Vs[0] + c0 * 8);
  gload_lds16(vP1, Vs[0] + c1 * 8);
  __syncthreads();

  int buf = 0;
  for (int kc = 0; kc < S; kc += 64) {
    if (kc + 64 < S) {
      const int kn = kc + 64;
      gload_lds16(kP0 + (size_t)kn * E, Ks[buf ^ 1] + c0 * 8);
      gload_lds16(kP1 + (size_t)kn * E, Ks[buf ^ 1] + c1 * 8);
      gload_lds16(vP0 + kn, Vs[buf ^ 1] + c0 * 8);
      gload_lds16(vP1 + kn, Vs[buf ^ 1] + c1 * 8);
    }
    const u16* ks = Ks[buf];
    const u16* vs = Vs[buf];

    // K B-frags: 4 key-tiles x 2 d-halves, shared by both q-tiles
    bf16x8 bk[4][2];
#pragma unroll
    for (int T = 0; T < 4; T++)
#pragma unroll
      for (int dh = 0; dh < 2; dh++)
        bk[T][dh] = *(const bf16x8*)(ks + (T * 16 + l16) * 64 +
                                     ((dh * 4 + quad) ^ sx) * 8);

    f32x4 s[2][4] = {};
#pragma unroll
    for (int qt = 0; qt < 2; qt++)
#pragma unroll
      for (int T = 0; T < 4; T++) {
        s[qt][T] = MFMA16(aq[qt][0], bk[T][0], s[qt][T]);
        s[qt][T] = MFMA16(aq[qt][1], bk[T][1], s[qt][T]);
      }

    const u64 mw = *(const u64*)(mb + (kc >> 5));
    const u32 mlo = (u32)mw, mhi = (u32)(mw >> 32);
    const int mk0 = (mlo >> l16) & 1, mk1 = (mlo >> (l16 + 16)) & 1;
    const int mk2 = (mhi >> l16) & 1, mk3 = (mhi >> (l16 + 16)) & 1;
    const float kl = (float)(kc + l16);

#pragma unroll
    for (int qt = 0; qt < 2; qt++)
#pragma unroll
      for (int r = 0; r < 4; r++) {
        const float fb = kl + fq[qt][r];
        const float e0 = fmaf(fabsf(fb), -K2, fmaf(s[qt][0][r], K1, K3));
        const float e1 = fmaf(fabsf(fb + 16.f), -K2, fmaf(s[qt][1][r], K1, K3));
        const float e2 = fmaf(fabsf(fb + 32.f), -K2, fmaf(s[qt][2][r], K1, K3));
        const float e3 = fmaf(fabsf(fb + 48.f), -K2, fmaf(s[qt][3][r], K1, K3));
        const float p0 = mk0 ? 0.f : __builtin_exp2f(e0);
        const float p1 = mk1 ? 0.f : __builtin_exp2f(e1);
        const float p2 = mk2 ? 0.f : __builtin_exp2f(e2);
        const float p3 = mk3 ? 0.f : __builtin_exp2f(e3);
        lr[qt][r] += (p0 + p1) + (p2 + p3);
        u32* pr = (u32*)(Pl[wave] + (qt * 16 + quad * 4 + r) * 72);
        pr[l16] = pack_bf2(p0, p1);        // storage pos 2*l16, 2*l16+1
        pr[16 + l16] = pack_bf2(p2, p3);   // storage pos 32+2*l16, +1
      }

    // intra-wave cross-lane P visibility
    asm volatile("s_waitcnt lgkmcnt(0)" ::: "memory");

    bf16x8 ap[2][2];
#pragma unroll
    for (int qt = 0; qt < 2; qt++)
#pragma unroll
      for (int kst = 0; kst < 2; kst++)
        ap[qt][kst] = *(const bf16x8*)(Pl[wave] + (qt * 16 + l16) * 72 +
                                       kst * 32 + quad * 8);
#pragma unroll
    for (int kst = 0; kst < 2; kst++)
#pragma unroll
      for (int tt = 0; tt < 4; tt++) {
        const bf16x8 bv = *(const bf16x8*)(vs + (tt * 16 + l16) * 64 +
                                           ((kst * 4 + quad) ^ sx) * 8);
        accO[0][tt] = MFMA16(ap[0][kst], bv, accO[0][tt]);
        accO[1][tt] = MFMA16(ap[1][kst], bv, accO[1][tt]);
      }

    __syncthreads();   // drain prefetch + protect staging buffers
    buf ^= 1;
  }

#pragma unroll
  for (int qt = 0; qt < 2; qt++)
#pragma unroll
    for (int r = 0; r < 4; r++) {
      float l = lr[qt][r];
      l += __shfl_xor(l, 1);
      l += __shfl_xor(l, 2);
      l += __shfl_xor(l, 4);
      l += __shfl_xor(l, 8);
      const float inv = 1.0f / l;
      const int qg = q0 + qt * 16 + quad * 4 + r;
#pragma unroll
      for (int tt = 0; tt < 4; tt++)
        O[((size_t)(b * S) + qg) * E + h * 64 + tt * 16 + l16] =
            f2bf(accO[qt][tt][r] * inv);
    }
}

// ---------------------------------------------------------------------------
extern "C" void kernel_launch(void* const* d_in, const int* in_sizes, int n_in,
                              void* d_out, int out_size, void* d_ws, size_t ws_size,
                              hipStream_t stream) {
  const float* x  = (const float*)d_in[0];
  const float* Wq = (const float*)d_in[1];
  const float* Wk = (const float*)d_in[2];
  const float* Wv = (const float*)d_in[3];
  const float* Wo = (const float*)d_in[4];
  const int* mask = (const int*)d_in[5];

  const int M = 4096, N = 1024, K = 1024;
  const int NE = M * N, NW = N * K;

  u16* xb    = (u16*)d_ws;
  u16* Wqkvb = xb + NE;
  u16* Wob   = Wqkvb + (size_t)3 * NW;
  u16* Qb    = Wob + NW;
  u16* Kb    = Qb + NE;
  u16* Vt    = Kb + NE;
  u16* Ao    = Vt + NE;
  u32* mbits = (u32*)(Ao + NE);

  dim3 blk(256);
  cvt_all<<<(NE + 4 * NW) / 2048, blk, 0, stream>>>(x, Wq, Wk, Wv, Wo,
                                                    xb, Wqkvb, Wob, NE, NW);
  pack_mask<<<1, 128, 0, stream>>>(mask, mbits);

  gemm_nt<1><<<dim3(3072 / 128, M / 128), blk, 0, stream>>>(
      xb, Wqkvb, Qb, Kb, Vt, M, 3072, K);
  attn_fwd<<<dim3(16, 32), blk, 0, stream>>>(Qb, Kb, Vt, mbits, Ao);
  gemm_nt<0><<<dim3(N / 128, M / 128), blk, 0, stream>>>(
      Ao, Wob, d_out, nullptr, nullptr, M, N, K);
}